// Round 23
// baseline (271.165 us; speedup 1.0000x reference)
//
#include <hip/hip_runtime.h>
#include <math.h>

#define IN_DIM 16
#define HIDN 128
#define NH 8
#define DHD 16
#define NTYPE 12
#define NLAYERS 4
#define NPG 5000
#define C1 656
#define C2 1312
#define C1Q (C1 / 4)
#define CAP 64
#define NPW 4
#define HREG (NPG / 2)
#define GEMM_SLOTS ((HREG + 63) / 64)   // 40
#define EDGE_SLOTS (HREG / NPW)         // 625
#define NSEG2 (NPG / NPW)               // 1250 pool segments per graph
#define POOLBASE 528                    // cols 0..527 old, 528..655 = last layer

typedef float vf4 __attribute__((ext_vector_type(4)));

__device__ __forceinline__ float gelu_t(float x) {
    float x3 = x * x * x;
    float u = 0.7978845608028654f * (x + 0.044715f * x3);
    return 0.5f * x * (1.0f + tanhf(u));
}

__device__ __forceinline__ unsigned pack_bf16(float lo, float hi) {
    unsigned a = __float_as_uint(lo);
    unsigned b = __float_as_uint(hi);
    a = (a + 0x7fffu + ((a >> 16) & 1u)) >> 16;
    b = (b + 0x7fffu + ((b >> 16) & 1u)) & 0xffff0000u;
    return a | b;
}

__device__ __forceinline__ float lrelu(float x) { return (x >= 0.f) ? x : 0.2f * x; }

// ---- init: ea table + zero bucket counters ----
__global__ __launch_bounds__(256) void k_init(const float* __restrict__ etab,
                                              const float* __restrict__ aed,
                                              float* __restrict__ ea, int* __restrict__ cnt,
                                              int N) {
    int i = blockIdx.x * 256 + threadIdx.x;
    if (i < NTYPE * NH) {
        int t = i / NH, hh = i % NH;
        float s = 0.f;
        #pragma unroll
        for (int d = 0; d < DHD; d++) s += etab[t * HIDN + hh * DHD + d] * aed[hh * DHD + d];
        ea[i] = s;
    }
    if (i < N) cnt[i] = 0;
}

// ---- pre: embed (wave-per-node) + edge bucketing, fused ----
__global__ __launch_bounds__(256) void k_pre(const float* __restrict__ feat,
                                             const float* __restrict__ We,
                                             const float* __restrict__ be,
                                             const int* __restrict__ srcp,
                                             const int* __restrict__ dstp,
                                             const int* __restrict__ etp,
                                             int* __restrict__ cnt,
                                             unsigned* __restrict__ payload2,
                                             float* __restrict__ out, int N, int E) {
    int bid = blockIdx.x, tid = threadIdx.x;
    int wave = tid >> 6, lane = tid & 63;
    int n = bid * NPW + wave;
    if (n < N) {
        float v = 0.f;
        if (lane < IN_DIM) {
            v = feat[n * IN_DIM + lane];
            if ((lane >= 2 && lane < 4) || lane >= 10) v = 0.f;
            out[(size_t)n * C2 + lane] = v;
        }
        float a0 = be[lane], a1 = be[lane + 64];
        #pragma unroll
        for (int k = 0; k < IN_DIM; k++) {
            float fk = __shfl(v, k);
            a0 += fk * We[k * HIDN + lane];
            a1 += fk * We[k * HIDN + lane + 64];
        }
        size_t ob = (size_t)n * C2 + IN_DIM;
        out[ob + lane] = gelu_t(a0);
        out[ob + lane + 64] = gelu_t(a1);
    }
    for (int e = bid * 256 + tid; e < E; e += gridDim.x * 256) {
        int d = dstp[e];
        int slot = atomicAdd(&cnt[d], 1);
        if (slot < CAP) {
            unsigned pk = (unsigned)srcp[e] | ((unsigned)etp[e] << 16);
            __builtin_nontemporal_store(pk, &payload2[(size_t)d * CAP + slot]);
        }
    }
}

// ---- per-layer GEMM: 64-row tiles, XCD-region mapped; split-W LDS ----
#define KC 64
__global__ __launch_bounds__(256) void k_gemm(const float* __restrict__ out,
                                              const float* __restrict__ W,
                                              const float* __restrict__ asf,
                                              const float* __restrict__ adf,
                                              unsigned* __restrict__ z16,
                                              float* __restrict__ slog,
                                              float* __restrict__ dlog, int prevbase, int N) {
    __shared__ float WcA[KC][64];
    __shared__ float WcB[KC][64];
    __shared__ float hc[64][KC + 4];
    int xcd = blockIdx.x & 7, slot = blockIdx.x >> 3;
    int g = xcd & 3, half = xcd >> 2;
    int base = g * NPG + half * HREG;
    int rend = base + HREG;
    int n0 = base + slot * 64;
    int t = threadIdx.x;
    int cg = t & 15, rg = t >> 4;
    int c0 = cg * 8;
    const float* hin = out + prevbase;
    float acc[4][8];
    #pragma unroll
    for (int i = 0; i < 4; i++)
        #pragma unroll
        for (int j = 0; j < 8; j++) acc[i][j] = 0.f;

    for (int k0 = 0; k0 < HIDN; k0 += KC) {
        for (int i = t; i < KC * 32; i += 256) {
            int kk = i >> 5, cc = (i & 31) << 2;
            float4 v = *(const float4*)&W[(k0 + kk) * HIDN + cc];
            int halfcol = (cc & ~4) >> 1;
            if (cc & 4) *(float4*)&WcB[kk][halfcol] = v;
            else *(float4*)&WcA[kk][halfcol] = v;
        }
        for (int i = t; i < 64 * (KC / 4); i += 256) {
            int rr = i / (KC / 4), kk = (i % (KC / 4)) * 4;
            int n = n0 + rr;
            float4 v = make_float4(0.f, 0.f, 0.f, 0.f);
            if (n < rend) v = *(const float4*)&hin[(size_t)n * C2 + k0 + kk];
            *(float4*)&hc[rr][kk] = v;
        }
        __syncthreads();
        for (int k = 0; k < KC; k++) {
            float4 w0 = *(float4*)&WcA[k][cg * 4];
            float4 w1 = *(float4*)&WcB[k][cg * 4];
            float hv[4];
            #pragma unroll
            for (int i = 0; i < 4; i++) hv[i] = hc[rg + 16 * i][k];
            #pragma unroll
            for (int i = 0; i < 4; i++) {
                acc[i][0] += hv[i] * w0.x;
                acc[i][1] += hv[i] * w0.y;
                acc[i][2] += hv[i] * w0.z;
                acc[i][3] += hv[i] * w0.w;
                acc[i][4] += hv[i] * w1.x;
                acc[i][5] += hv[i] * w1.y;
                acc[i][6] += hv[i] * w1.z;
                acc[i][7] += hv[i] * w1.w;
            }
        }
        __syncthreads();
    }
    float4 s0 = *(const float4*)&asf[c0];
    float4 s1 = *(const float4*)&asf[c0 + 4];
    float4 d0 = *(const float4*)&adf[c0];
    float4 d1 = *(const float4*)&adf[c0 + 4];
    #pragma unroll
    for (int i = 0; i < 4; i++) {
        int n = n0 + rg + 16 * i;
        float ps = acc[i][0] * s0.x + acc[i][1] * s0.y + acc[i][2] * s0.z + acc[i][3] * s0.w +
                   acc[i][4] * s1.x + acc[i][5] * s1.y + acc[i][6] * s1.z + acc[i][7] * s1.w;
        float pd = acc[i][0] * d0.x + acc[i][1] * d0.y + acc[i][2] * d0.z + acc[i][3] * d0.w +
                   acc[i][4] * d1.x + acc[i][5] * d1.y + acc[i][6] * d1.z + acc[i][7] * d1.w;
        ps += __shfl_xor(ps, 1);
        pd += __shfl_xor(pd, 1);
        unsigned u[8];
        #pragma unroll
        for (int j = 0; j < 8; j++) {
            float other = __shfl_xor(acc[i][j], 8);
            u[j] = pack_bf16(acc[i][j], other);
        }
        if (n < rend) {
            if (cg < 8) {
                *(uint4*)&z16[(size_t)n * 64 + c0] = make_uint4(u[0], u[1], u[2], u[3]);
                *(uint4*)&z16[(size_t)n * 64 + c0 + 4] = make_uint4(u[4], u[5], u[6], u[7]);
            }
            if ((cg & 1) == 0) {
                slog[n * NH + (cg >> 1)] = ps;
                dlog[n * NH + (cg >> 1)] = pd;
            }
        }
    }
}

// ---- per-layer edge aggregation; last layer also emits pool partials ----
__global__ __launch_bounds__(256) void k_edge(const int* __restrict__ cnt,
                                              const unsigned* __restrict__ payload2,
                                              const float* __restrict__ slog,
                                              const float* __restrict__ dlog,
                                              const float* __restrict__ ea,
                                              const unsigned* __restrict__ z16,
                                              float* __restrict__ out,
                                              float* __restrict__ gpart, int prevbase,
                                              int curbase, int dopool, int N) {
    int tid = threadIdx.x;
    int wave = tid >> 6, lane = tid & 63;
    int xcd = blockIdx.x & 7, slot = blockIdx.x >> 3;
    int g = xcd & 3, half = xcd >> 2;
    int unit = g * (NPG / NPW) + half * EDGE_SLOTS + slot;
    int n = unit * NPW + wave;
    bool active = (n < N);
    __shared__ float lbuf[NPW][CAP * NH];
    __shared__ unsigned pbuf[NPW][CAP];
    __shared__ float dl[NPW][NH];
    __shared__ float red[NPW][NH];
    __shared__ float sea[NTYPE * NH];
    __shared__ float pm[NPW][HIDN];

    if (tid < NTYPE * NH) sea[tid] = ea[tid];

    int cntE = 0;
    if (active) {
        cntE = cnt[n];
        if (cntE > CAP) cntE = CAP;
        if (lane < NH) dl[wave][lane] = dlog[n * NH + lane];
    }
    if (lane < cntE) pbuf[wave][lane] = payload2[(size_t)n * CAP + lane];
    __syncthreads();

    int o = lane & 1;
    int eoff = lane >> 1;
    float4 dl4 = *(float4*)&dl[wave][o * 4];
    float4 ssum4 = make_float4(0.f, 0.f, 0.f, 0.f);
    #pragma unroll
    for (int base = 0; base < CAP; base += 32) {
        int el = base + eoff;
        if (el < cntE) {
            unsigned pk = pbuf[wave][el];
            int src = pk & 0xffff;
            int et = pk >> 16;
            float4 s4 = *(const float4*)&slog[src * NH + o * 4];
            float4 e4 = *(float4*)&sea[et * NH + o * 4];
            float4 ex;
            ex.x = __expf(lrelu(s4.x + dl4.x + e4.x));
            ex.y = __expf(lrelu(s4.y + dl4.y + e4.y));
            ex.z = __expf(lrelu(s4.z + dl4.z + e4.z));
            ex.w = __expf(lrelu(s4.w + dl4.w + e4.w));
            *(float4*)&lbuf[wave][el * NH + o * 4] = ex;
            ssum4.x += ex.x;
            ssum4.y += ex.y;
            ssum4.z += ex.z;
            ssum4.w += ex.w;
        }
    }
    #pragma unroll
    for (int m = 2; m <= 32; m <<= 1) {
        ssum4.x += __shfl_xor(ssum4.x, m);
        ssum4.y += __shfl_xor(ssum4.y, m);
        ssum4.z += __shfl_xor(ssum4.z, m);
        ssum4.w += __shfl_xor(ssum4.w, m);
    }
    if (lane < 2) {
        float4 r4;
        r4.x = 1.0f / (ssum4.x + 1e-9f);
        r4.y = 1.0f / (ssum4.y + 1e-9f);
        r4.z = 1.0f / (ssum4.z + 1e-9f);
        r4.w = 1.0f / (ssum4.w + 1e-9f);
        *(float4*)&red[wave][o * 4] = r4;
    }
    __syncthreads();

    int h1 = lane >> 4, h2 = h1 + 4;
    float r1 = red[wave][h1], r2 = red[wave][h2];
    float a0 = 0.f, a1 = 0.f;
    int e = 0;
    for (; e + 7 < cntE; e += 8) {
        unsigned v[8];
        #pragma unroll
        for (int j = 0; j < 8; j++) {
            unsigned s = pbuf[wave][e + j] & 0xffff;
            v[j] = z16[(size_t)s * 64 + lane];
        }
        #pragma unroll
        for (int j = 0; j < 8; j++) {
            float l0 = lbuf[wave][(e + j) * NH + h1];
            float l1 = lbuf[wave][(e + j) * NH + h2];
            a0 += l0 * __uint_as_float(v[j] << 16);
            a1 += l1 * __uint_as_float(v[j] & 0xffff0000u);
        }
    }
    for (; e < cntE; e++) {
        unsigned s0 = pbuf[wave][e] & 0xffff;
        unsigned v0 = z16[(size_t)s0 * 64 + lane];
        a0 += lbuf[wave][e * NH + h1] * __uint_as_float(v0 << 16);
        a1 += lbuf[wave][e * NH + h2] * __uint_as_float(v0 & 0xffff0000u);
    }
    float o0 = 0.f, o1 = 0.f;
    if (active) {
        a0 *= r1;
        a1 *= r2;
        size_t rowb = (size_t)n * C2;
        o0 = out[rowb + prevbase + lane] + gelu_t(a0);
        o1 = out[rowb + prevbase + lane + 64] + gelu_t(a1);
        out[rowb + curbase + lane] = o0;
        out[rowb + curbase + lane + 64] = o1;
    }
    // fused pool-partial on the last layer: this block owns 4 rows of the graph
    if (dopool) {
        pm[wave][lane] = active ? o0 : -3.4e38f;
        pm[wave][lane + 64] = active ? o1 : -3.4e38f;
        __syncthreads();
        for (int c = tid; c < C1; c += 256) {
            float m;
            if (c < POOLBASE) {
                m = -3.4e38f;
                #pragma unroll
                for (int r = 0; r < NPW; r++) {
                    int nn = unit * NPW + r;
                    if (nn < N) m = fmaxf(m, out[(size_t)nn * C2 + c]);
                }
            } else {
                int cc = c - POOLBASE;
                m = fmaxf(fmaxf(pm[0][cc], pm[1][cc]), fmaxf(pm[2][cc], pm[3][cc]));
            }
            gpart[(size_t)unit * C1 + c] = m;
        }
    }
}

// ---- pool final: wave per (graph,col), reduce 1250 segments ----
__global__ __launch_bounds__(256) void k_pool_final(const float* __restrict__ gpart,
                                                    float* __restrict__ gemb, int B) {
    int w = blockIdx.x * 4 + (threadIdx.x >> 6);
    int lane = threadIdx.x & 63;
    if (w >= B * C1) return;
    int b = w / C1, c = w % C1;
    float m = -3.4e38f;
    for (int s = lane; s < NSEG2; s += 64) m = fmaxf(m, gpart[(size_t)(b * NSEG2 + s) * C1 + c]);
    #pragma unroll
    for (int k = 1; k < 64; k <<= 1) m = fmaxf(m, __shfl_xor(m, k));
    if (lane == 0) gemb[w] = m;
}

// ---- broadcast: grid-stride, nt-stores ----
__global__ __launch_bounds__(256) void k_bcast(const float* __restrict__ gemb,
                                               float* __restrict__ out, int N) {
    size_t total = (size_t)N * C1Q;
    for (size_t idx = (size_t)blockIdx.x * 256 + threadIdx.x; idx < total;
         idx += (size_t)gridDim.x * 256) {
        int n = idx / C1Q, c4 = idx % C1Q;
        int b = n / NPG;
        vf4 g = *(const vf4*)&gemb[b * C1 + c4 * 4];
        __builtin_nontemporal_store(g, (vf4*)&out[(size_t)n * C2 + C1 + c4 * 4]);
    }
}

extern "C" void kernel_launch(void* const* d_in, const int* in_sizes, int n_in, void* d_out,
                              int out_size, void* d_ws, size_t ws_size, hipStream_t stream) {
    const float* feat = (const float*)d_in[0];
    const float* etab = (const float*)d_in[1];
    const float* We = (const float*)d_in[2];
    const float* be = (const float*)d_in[3];
    const float* Wc = (const float*)d_in[4];
    const float* a_src = (const float*)d_in[5];
    const float* a_dst = (const float*)d_in[6];
    const float* a_edge = (const float*)d_in[7];
    const int* eidx = (const int*)d_in[8];
    const int* etype = (const int*)d_in[9];
    float* out = (float*)d_out;

    const int N = in_sizes[0] / IN_DIM;   // 20000
    const int E = in_sizes[9];            // 660000
    const int B = N / NPG;                // 4

    const int* srcp = eidx;
    const int* dstp = eidx + E;

    char* w = (char*)d_ws;
    size_t off = 0;
    auto carve = [&](size_t bytes) {
        char* p = w + off;
        off = (off + bytes + 255) & ~(size_t)255;
        return p;
    };
    unsigned* z16 = (unsigned*)carve((size_t)N * 64 * 4);
    float* slog = (float*)carve((size_t)N * NH * 4);
    float* dlog = (float*)carve((size_t)N * NH * 4);
    float* ea = (float*)carve(NTYPE * NH * 4);
    int* cnt = (int*)carve((size_t)N * 4);
    unsigned* payload2 = (unsigned*)carve((size_t)N * CAP * 4);
    float* gpart = (float*)carve((size_t)B * NSEG2 * C1 * 4);
    float* gemb = (float*)carve((size_t)B * C1 * 4);
    (void)ws_size;

    k_init<<<(N + 255) / 256, 256, 0, stream>>>(etab, a_edge, ea, cnt, N);
    k_pre<<<(N + NPW - 1) / NPW, 256, 0, stream>>>(feat, We, be, srcp, dstp, etype, cnt,
                                                   payload2, out, N, E);

    for (int l = 0; l < NLAYERS; l++) {
        int prevbase = IN_DIM + HIDN * l;
        int curbase = IN_DIM + HIDN * (l + 1);
        k_gemm<<<8 * GEMM_SLOTS, 256, 0, stream>>>(out, Wc, a_src, a_dst, z16, slog, dlog,
                                                   prevbase, N);
        k_edge<<<8 * EDGE_SLOTS, 256, 0, stream>>>(cnt, payload2, slog, dlog, ea, z16, out,
                                                   gpart, prevbase, curbase,
                                                   (l == NLAYERS - 1) ? 1 : 0, N);
    }

    k_pool_final<<<(B * C1 + 3) / 4, 256, 0, stream>>>(gpart, gemb, B);
    k_bcast<<<2048, 256, 0, stream>>>(gemb, out, N);
}

// Round 24
// 251.657 us; speedup vs baseline: 1.0775x; 1.0775x over previous
//
#include <hip/hip_runtime.h>
#include <math.h>

#define IN_DIM 16
#define HIDN 128
#define NH 8
#define DHD 16
#define NTYPE 12
#define NLAYERS 4
#define NPG 5000
#define NSEGP 250
#define RPS (NPG / NSEGP)
#define C1 656
#define C2 1312
#define C1Q (C1 / 4)
#define CAP 64
#define NPW 4
#define HREG (NPG / 2)
#define GEMM_SLOTS ((HREG + 63) / 64)   // 40
#define EDGE_SLOTS (HREG / NPW)         // 625

__device__ __forceinline__ float gelu_t(float x) {
    float x3 = x * x * x;
    float u = 0.7978845608028654f * (x + 0.044715f * x3);
    return 0.5f * x * (1.0f + tanhf(u));
}

__device__ __forceinline__ unsigned pack_bf16(float lo, float hi) {
    unsigned a = __float_as_uint(lo);
    unsigned b = __float_as_uint(hi);
    a = (a + 0x7fffu + ((a >> 16) & 1u)) >> 16;
    b = (b + 0x7fffu + ((b >> 16) & 1u)) & 0xffff0000u;
    return a | b;
}

__device__ __forceinline__ float lrelu(float x) { return (x >= 0.f) ? x : 0.2f * x; }

// ---- init: ea table + zero bucket counters ----
__global__ __launch_bounds__(256) void k_init(const float* __restrict__ etab,
                                              const float* __restrict__ aed,
                                              float* __restrict__ ea, int* __restrict__ cnt,
                                              int N) {
    int i = blockIdx.x * 256 + threadIdx.x;
    if (i < NTYPE * NH) {
        int t = i / NH, hh = i % NH;
        float s = 0.f;
        #pragma unroll
        for (int d = 0; d < DHD; d++) s += etab[t * HIDN + hh * DHD + d] * aed[hh * DHD + d];
        ea[i] = s;
    }
    if (i < N) cnt[i] = 0;
}

// ---- pre: embed (wave-per-node) + edge bucketing, fused ----
__global__ __launch_bounds__(256) void k_pre(const float* __restrict__ feat,
                                             const float* __restrict__ We,
                                             const float* __restrict__ be,
                                             const int* __restrict__ srcp,
                                             const int* __restrict__ dstp,
                                             const int* __restrict__ etp,
                                             int* __restrict__ cnt,
                                             unsigned* __restrict__ payload2,
                                             float* __restrict__ out, int N, int E) {
    int bid = blockIdx.x, tid = threadIdx.x;
    int wave = tid >> 6, lane = tid & 63;
    int n = bid * NPW + wave;
    if (n < N) {
        float v = 0.f;
        if (lane < IN_DIM) {
            v = feat[n * IN_DIM + lane];
            if ((lane >= 2 && lane < 4) || lane >= 10) v = 0.f;
            out[(size_t)n * C2 + lane] = v;
        }
        float a0 = be[lane], a1 = be[lane + 64];
        #pragma unroll
        for (int k = 0; k < IN_DIM; k++) {
            float fk = __shfl(v, k);
            a0 += fk * We[k * HIDN + lane];
            a1 += fk * We[k * HIDN + lane + 64];
        }
        size_t ob = (size_t)n * C2 + IN_DIM;
        out[ob + lane] = gelu_t(a0);
        out[ob + lane + 64] = gelu_t(a1);
    }
    // bucket: grid-stride over edges
    for (int e = bid * 256 + tid; e < E; e += gridDim.x * 256) {
        int d = dstp[e];
        int slot = atomicAdd(&cnt[d], 1);
        if (slot < CAP)
            payload2[(size_t)d * CAP + slot] = (unsigned)srcp[e] | ((unsigned)etp[e] << 16);
    }
}

// ---- per-layer GEMM: 64-row tiles, XCD-region mapped; split-W LDS ----
#define KC 64
__global__ __launch_bounds__(256) void k_gemm(const float* __restrict__ out,
                                              const float* __restrict__ W,
                                              const float* __restrict__ asf,
                                              const float* __restrict__ adf,
                                              unsigned* __restrict__ z16,
                                              float* __restrict__ slog,
                                              float* __restrict__ dlog, int prevbase, int N) {
    __shared__ float WcA[KC][64];
    __shared__ float WcB[KC][64];
    __shared__ float hc[64][KC + 4];
    int xcd = blockIdx.x & 7, slot = blockIdx.x >> 3;
    int g = xcd & 3, half = xcd >> 2;
    int base = g * NPG + half * HREG;
    int rend = base + HREG;
    int n0 = base + slot * 64;
    int t = threadIdx.x;
    int cg = t & 15, rg = t >> 4;
    int c0 = cg * 8;
    const float* hin = out + prevbase;
    float acc[4][8];
    #pragma unroll
    for (int i = 0; i < 4; i++)
        #pragma unroll
        for (int j = 0; j < 8; j++) acc[i][j] = 0.f;

    for (int k0 = 0; k0 < HIDN; k0 += KC) {
        for (int i = t; i < KC * 32; i += 256) {
            int kk = i >> 5, cc = (i & 31) << 2;
            float4 v = *(const float4*)&W[(k0 + kk) * HIDN + cc];
            int halfcol = (cc & ~4) >> 1;
            if (cc & 4) *(float4*)&WcB[kk][halfcol] = v;
            else *(float4*)&WcA[kk][halfcol] = v;
        }
        for (int i = t; i < 64 * (KC / 4); i += 256) {
            int rr = i / (KC / 4), kk = (i % (KC / 4)) * 4;
            int n = n0 + rr;
            float4 v = make_float4(0.f, 0.f, 0.f, 0.f);
            if (n < rend) v = *(const float4*)&hin[(size_t)n * C2 + k0 + kk];
            *(float4*)&hc[rr][kk] = v;
        }
        __syncthreads();
        for (int k = 0; k < KC; k++) {
            float4 w0 = *(float4*)&WcA[k][cg * 4];
            float4 w1 = *(float4*)&WcB[k][cg * 4];
            float hv[4];
            #pragma unroll
            for (int i = 0; i < 4; i++) hv[i] = hc[rg + 16 * i][k];
            #pragma unroll
            for (int i = 0; i < 4; i++) {
                acc[i][0] += hv[i] * w0.x;
                acc[i][1] += hv[i] * w0.y;
                acc[i][2] += hv[i] * w0.z;
                acc[i][3] += hv[i] * w0.w;
                acc[i][4] += hv[i] * w1.x;
                acc[i][5] += hv[i] * w1.y;
                acc[i][6] += hv[i] * w1.z;
                acc[i][7] += hv[i] * w1.w;
            }
        }
        __syncthreads();
    }
    float4 s0 = *(const float4*)&asf[c0];
    float4 s1 = *(const float4*)&asf[c0 + 4];
    float4 d0 = *(const float4*)&adf[c0];
    float4 d1 = *(const float4*)&adf[c0 + 4];
    #pragma unroll
    for (int i = 0; i < 4; i++) {
        int n = n0 + rg + 16 * i;
        float ps = acc[i][0] * s0.x + acc[i][1] * s0.y + acc[i][2] * s0.z + acc[i][3] * s0.w +
                   acc[i][4] * s1.x + acc[i][5] * s1.y + acc[i][6] * s1.z + acc[i][7] * s1.w;
        float pd = acc[i][0] * d0.x + acc[i][1] * d0.y + acc[i][2] * d0.z + acc[i][3] * d0.w +
                   acc[i][4] * d1.x + acc[i][5] * d1.y + acc[i][6] * d1.z + acc[i][7] * d1.w;
        ps += __shfl_xor(ps, 1);
        pd += __shfl_xor(pd, 1);
        unsigned u[8];
        #pragma unroll
        for (int j = 0; j < 8; j++) {
            float other = __shfl_xor(acc[i][j], 8);
            u[j] = pack_bf16(acc[i][j], other);
        }
        if (n < rend) {
            if (cg < 8) {
                *(uint4*)&z16[(size_t)n * 64 + c0] = make_uint4(u[0], u[1], u[2], u[3]);
                *(uint4*)&z16[(size_t)n * 64 + c0 + 4] = make_uint4(u[4], u[5], u[6], u[7]);
            }
            if ((cg & 1) == 0) {
                slog[n * NH + (cg >> 1)] = ps;
                dlog[n * NH + (cg >> 1)] = pd;
            }
        }
    }
}

// ---- per-layer edge aggregation: bucketed payload, out-resident residual ----
__global__ __launch_bounds__(256) void k_edge(const int* __restrict__ cnt,
                                              const unsigned* __restrict__ payload2,
                                              const float* __restrict__ slog,
                                              const float* __restrict__ dlog,
                                              const float* __restrict__ ea,
                                              const unsigned* __restrict__ z16,
                                              float* __restrict__ out, int prevbase,
                                              int curbase, int N) {
    int wave = threadIdx.x >> 6, lane = threadIdx.x & 63;
    int xcd = blockIdx.x & 7, slot = blockIdx.x >> 3;
    int g = xcd & 3, half = xcd >> 2;
    int unit = g * (NPG / NPW) + half * EDGE_SLOTS + slot;
    int n = unit * NPW + wave;
    bool active = (n < N);
    __shared__ float lbuf[NPW][CAP * NH];
    __shared__ unsigned pbuf[NPW][CAP];
    __shared__ float dl[NPW][NH];
    __shared__ float red[NPW][NH];
    __shared__ float sea[NTYPE * NH];

    if (threadIdx.x < NTYPE * NH) sea[threadIdx.x] = ea[threadIdx.x];

    int cntE = 0;
    if (active) {
        cntE = cnt[n];
        if (cntE > CAP) cntE = CAP;
        if (lane < NH) dl[wave][lane] = dlog[n * NH + lane];
    }
    if (lane < cntE) pbuf[wave][lane] = payload2[(size_t)n * CAP + lane];
    __syncthreads();

    int o = lane & 1;
    int eoff = lane >> 1;
    float4 dl4 = *(float4*)&dl[wave][o * 4];
    float4 ssum4 = make_float4(0.f, 0.f, 0.f, 0.f);
    #pragma unroll
    for (int base = 0; base < CAP; base += 32) {
        int el = base + eoff;
        if (el < cntE) {
            unsigned pk = pbuf[wave][el];
            int src = pk & 0xffff;
            int et = pk >> 16;
            float4 s4 = *(const float4*)&slog[src * NH + o * 4];
            float4 e4 = *(float4*)&sea[et * NH + o * 4];
            float4 ex;
            ex.x = __expf(lrelu(s4.x + dl4.x + e4.x));
            ex.y = __expf(lrelu(s4.y + dl4.y + e4.y));
            ex.z = __expf(lrelu(s4.z + dl4.z + e4.z));
            ex.w = __expf(lrelu(s4.w + dl4.w + e4.w));
            *(float4*)&lbuf[wave][el * NH + o * 4] = ex;
            ssum4.x += ex.x;
            ssum4.y += ex.y;
            ssum4.z += ex.z;
            ssum4.w += ex.w;
        }
    }
    #pragma unroll
    for (int m = 2; m <= 32; m <<= 1) {
        ssum4.x += __shfl_xor(ssum4.x, m);
        ssum4.y += __shfl_xor(ssum4.y, m);
        ssum4.z += __shfl_xor(ssum4.z, m);
        ssum4.w += __shfl_xor(ssum4.w, m);
    }
    if (lane < 2) {
        float4 r4;
        r4.x = 1.0f / (ssum4.x + 1e-9f);
        r4.y = 1.0f / (ssum4.y + 1e-9f);
        r4.z = 1.0f / (ssum4.z + 1e-9f);
        r4.w = 1.0f / (ssum4.w + 1e-9f);
        *(float4*)&red[wave][o * 4] = r4;
    }
    __syncthreads();

    int h1 = lane >> 4, h2 = h1 + 4;
    float r1 = red[wave][h1], r2 = red[wave][h2];
    float a0 = 0.f, a1 = 0.f;
    int e = 0;
    for (; e + 7 < cntE; e += 8) {
        unsigned v[8];
        #pragma unroll
        for (int j = 0; j < 8; j++) {
            unsigned s = pbuf[wave][e + j] & 0xffff;
            v[j] = z16[(size_t)s * 64 + lane];
        }
        #pragma unroll
        for (int j = 0; j < 8; j++) {
            float l0 = lbuf[wave][(e + j) * NH + h1];
            float l1 = lbuf[wave][(e + j) * NH + h2];
            a0 += l0 * __uint_as_float(v[j] << 16);
            a1 += l1 * __uint_as_float(v[j] & 0xffff0000u);
        }
    }
    for (; e < cntE; e++) {
        unsigned s0 = pbuf[wave][e] & 0xffff;
        unsigned v0 = z16[(size_t)s0 * 64 + lane];
        a0 += lbuf[wave][e * NH + h1] * __uint_as_float(v0 << 16);
        a1 += lbuf[wave][e * NH + h2] * __uint_as_float(v0 & 0xffff0000u);
    }
    if (active) {
        a0 *= r1;
        a1 *= r2;
        size_t rowb = (size_t)n * C2;
        float o0 = out[rowb + prevbase + lane] + gelu_t(a0);
        float o1 = out[rowb + prevbase + lane + 64] + gelu_t(a1);
        out[rowb + curbase + lane] = o0;
        out[rowb + curbase + lane + 64] = o1;
    }
}

// ---- graph max-pool: XCD-region-mapped partial ----
__global__ __launch_bounds__(256) void k_pool_partial(const float* __restrict__ out,
                                                      float* __restrict__ gpart) {
    int xcd = blockIdx.x & 7, slot = blockIdx.x >> 3;   // slot 0..124
    int b = xcd & 3, half = xcd >> 2;
    int seg = half * (NSEGP / 2) + slot;
    int n0 = b * NPG + seg * RPS;
    for (int c = threadIdx.x; c < C1; c += 256) {
        float m = -3.4e38f;
        #pragma unroll
        for (int i = 0; i < RPS; i++) m = fmaxf(m, out[(size_t)(n0 + i) * C2 + c]);
        gpart[(size_t)(b * NSEGP + seg) * C1 + c] = m;
    }
}

__global__ __launch_bounds__(256) void k_pool_final(const float* __restrict__ gpart,
                                                    float* __restrict__ gemb, int B) {
    int w = blockIdx.x * 4 + (threadIdx.x >> 6);
    int lane = threadIdx.x & 63;
    if (w >= B * C1) return;
    int b = w / C1, c = w % C1;
    float m = -3.4e38f;
    for (int s = lane; s < NSEGP; s += 64) m = fmaxf(m, gpart[(size_t)(b * NSEGP + s) * C1 + c]);
    #pragma unroll
    for (int k = 1; k < 64; k <<= 1) m = fmaxf(m, __shfl_xor(m, k));
    if (lane == 0) gemb[w] = m;
}

__global__ __launch_bounds__(256) void k_bcast(const float* __restrict__ gemb,
                                               float* __restrict__ out, int N) {
    int idx = blockIdx.x * 256 + threadIdx.x;
    if (idx < N * C1Q) {
        int n = idx / C1Q, c4 = idx % C1Q;
        int b = n / NPG;
        float4 g = *(const float4*)&gemb[b * C1 + c4 * 4];
        *(float4*)&out[(size_t)n * C2 + C1 + c4 * 4] = g;
    }
}

extern "C" void kernel_launch(void* const* d_in, const int* in_sizes, int n_in, void* d_out,
                              int out_size, void* d_ws, size_t ws_size, hipStream_t stream) {
    const float* feat = (const float*)d_in[0];
    const float* etab = (const float*)d_in[1];
    const float* We = (const float*)d_in[2];
    const float* be = (const float*)d_in[3];
    const float* Wc = (const float*)d_in[4];
    const float* a_src = (const float*)d_in[5];
    const float* a_dst = (const float*)d_in[6];
    const float* a_edge = (const float*)d_in[7];
    const int* eidx = (const int*)d_in[8];
    const int* etype = (const int*)d_in[9];
    float* out = (float*)d_out;

    const int N = in_sizes[0] / IN_DIM;   // 20000
    const int E = in_sizes[9];            // 660000
    const int B = N / NPG;                // 4

    const int* srcp = eidx;
    const int* dstp = eidx + E;

    char* w = (char*)d_ws;
    size_t off = 0;
    auto carve = [&](size_t bytes) {
        char* p = w + off;
        off = (off + bytes + 255) & ~(size_t)255;
        return p;
    };
    unsigned* z16 = (unsigned*)carve((size_t)N * 64 * 4);
    float* slog = (float*)carve((size_t)N * NH * 4);
    float* dlog = (float*)carve((size_t)N * NH * 4);
    float* ea = (float*)carve(NTYPE * NH * 4);
    int* cnt = (int*)carve((size_t)N * 4);
    unsigned* payload2 = (unsigned*)carve((size_t)N * CAP * 4);
    float* gpart = (float*)carve((size_t)B * NSEGP * C1 * 4);
    float* gemb = (float*)carve((size_t)B * C1 * 4);
    (void)ws_size;

    k_init<<<(N + 255) / 256, 256, 0, stream>>>(etab, a_edge, ea, cnt, N);
    k_pre<<<(N + NPW - 1) / NPW, 256, 0, stream>>>(feat, We, be, srcp, dstp, etype, cnt,
                                                   payload2, out, N, E);

    for (int l = 0; l < NLAYERS; l++) {
        int prevbase = IN_DIM + HIDN * l;
        int curbase = IN_DIM + HIDN * (l + 1);
        k_gemm<<<8 * GEMM_SLOTS, 256, 0, stream>>>(out, Wc, a_src, a_dst, z16, slog, dlog,
                                                   prevbase, N);
        k_edge<<<8 * EDGE_SLOTS, 256, 0, stream>>>(cnt, payload2, slog, dlog, ea, z16, out,
                                                   prevbase, curbase, N);
    }

    k_pool_partial<<<8 * (NSEGP / 2), 256, 0, stream>>>(out, gpart);
    k_pool_final<<<(B * C1 + 3) / 4, 256, 0, stream>>>(gpart, gemb, B);
    k_bcast<<<((size_t)N * C1Q + 255) / 256, 256, 0, stream>>>(gemb, out, N);
}